// Round 5
// baseline (760.584 us; speedup 1.0000x reference)
//
#include <hip/hip_runtime.h>
#include <hip/hip_bf16.h>
#include <stdint.h>

// FusedMoEBlock R4: LDS-free GEMMs. A (bf16) fragments loaded directly from
// global (L2-hot); B (f32) fragments loaded as 8 strided dwords + in-register
// cvt to bf16. No barriers in the K loop -> pure TLP latency hiding.
// T=2048,H=2048,E=64,I=512,IS=1024,k<=8.
// d_out = [shared_out (T*H f32) | routed (T*H f32)].

#define H_DIM 2048
#define E_NUM 64
#define I_DIM 512
#define IS_DIM 1024
#define CAP 512     // max tokens/expert (mean 192, max~245; 24 sigma)
#define TOPK_MAX 8

typedef float f32x4 __attribute__((ext_vector_type(4)));
typedef __bf16 bf16x8 __attribute__((ext_vector_type(8)));

__device__ __forceinline__ uint16_t f2bf(float f) {
  union { float f; uint32_t u; } v;
  v.f = f;
  uint32_t r = (v.u + 0x7FFFu + ((v.u >> 16) & 1u)) >> 16;  // RNE
  return (uint16_t)r;
}
__device__ __forceinline__ uint32_t pack2(float a, float b) {
  return (uint32_t)f2bf(a) | ((uint32_t)f2bf(b) << 16);
}
__device__ __forceinline__ float bf2f(uint16_t b) {
  union { uint32_t u; float f; } v;
  v.u = (uint32_t)b << 16;
  return v.f;
}

// ---------------- router: logits -> sigmoid -> top-k -> buckets; writes xb --
__global__ __launch_bounds__(256) void router_kernel(
    const float* __restrict__ x, const float* __restrict__ gw,
    const int* __restrict__ topk_ptr, int* __restrict__ cnt,
    int* __restrict__ bucket, float* __restrict__ bw,
    uint16_t* __restrict__ xb) {
  const int t = blockIdx.x;
  const int tid = threadIdx.x;
  __shared__ float xs[H_DIM];
  __shared__ float logits[E_NUM];
#pragma unroll
  for (int i = 0; i < 2; ++i) {
    int idx = tid + i * 256;
    *(float4*)(&xs[idx * 4]) = *(const float4*)(x + (size_t)t * H_DIM + idx * 4);
  }
  __syncthreads();
  {  // fused f32->bf16 conversion of this token's row
    const float* p = &xs[tid * 8];
    uint4 o;
    o.x = pack2(p[0], p[1]);
    o.y = pack2(p[2], p[3]);
    o.z = pack2(p[4], p[5]);
    o.w = pack2(p[6], p[7]);
    ((uint4*)(xb + (size_t)t * H_DIM))[tid] = o;
  }
  const int lane = tid & 63, wid = tid >> 6;
  float xr[32];
#pragma unroll
  for (int it = 0; it < 32; ++it) xr[it] = xs[lane + 64 * it];
  for (int eo = 0; eo < 16; ++eo) {
    int e = wid + eo * 4;
    const float* g = gw + (size_t)e * H_DIM;
    float acc = 0.f;
#pragma unroll
    for (int it = 0; it < 32; ++it) acc += xr[it] * g[lane + 64 * it];
#pragma unroll
    for (int off = 32; off; off >>= 1) acc += __shfl_xor(acc, off);
    if (lane == 0) logits[e] = acc;
  }
  __syncthreads();
  if (wid == 0) {
    int k = topk_ptr[0];
    if (k > TOPK_MAX) k = TOPK_MAX;
    // sigmoid; pre-topk normalize is scale-invariant -> skipped
    float v = 1.f / (1.f + expf(-logits[lane]));
    float s = 0.f, myw = 0.f;
    int mye = 0;
    for (int j = 0; j < k; ++j) {
      float m = v;
      int mi = lane;
#pragma unroll
      for (int off = 32; off; off >>= 1) {
        float ov = __shfl_xor(m, off);
        int oi = __shfl_xor(mi, off);
        if (ov > m || (ov == m && oi < mi)) { m = ov; mi = oi; }
      }
      if (lane == j) { myw = m; mye = mi; }
      if (lane == mi) v = -1e30f;
      s += m;
    }
    if (lane < k) {
      float w = myw / s;
      int pos = atomicAdd(&cnt[mye], 1);
      if (pos < CAP) {
        bucket[mye * CAP + pos] = t * 8 + lane;  // token*8 + choice slot
        bw[mye * CAP + pos] = w;
      }
    }
  }
}

// ---------------- gate+up GEMM + silu*mul -> act (bf16), LDS-free ----------
// 4 waves: 2-way M split (wm) x 2-way N split (wn). Per 32-k slab each lane
// loads A frags (uint4, bf16) and B frags (8 strided f32 -> cvt bf16).
template <int BM, int BN, bool GATHER>
__global__ __launch_bounds__(256) void ffn_in(
    const uint16_t* __restrict__ xb, const float* __restrict__ Wg,
    const float* __restrict__ Wu, uint16_t* __restrict__ act,
    const int* __restrict__ cnt, const int* __restrict__ bucket,
    const int K, const int ldb) {
  constexpr int MF = BM / 32;  // row frags per wave
  constexpr int NF = BN / 32;  // col frags per wave

  int e = 0, nt, mt0, mtE, n_e;
  const float *Bg, *Bu;
  uint16_t* actE;
  if constexpr (GATHER) {
    e = blockIdx.x;  // gridDim.x=64 -> same-e blocks on XCD e%8
    nt = blockIdx.y;
    n_e = min(cnt[e], CAP);
    mt0 = 0;
    mtE = (n_e + BM - 1) / BM;
    const size_t wo = (size_t)e * K * ldb;
    Bg = Wg + wo;
    Bu = Wu + wo;
    actE = act + (size_t)e * CAP * ldb;
  } else {
    nt = blockIdx.x;
    mt0 = blockIdx.y;
    mtE = mt0 + 1;
    n_e = gridDim.y * BM;
    Bg = Wg;
    Bu = Wu;
    actE = act;
  }
  if (mt0 * BM >= n_e) return;

  const int tid = threadIdx.x;
  const int lane = tid & 63, wid = tid >> 6;
  const int wm = wid >> 1, wn = wid & 1;
  const int fr = lane & 15, kg = lane >> 4;

  const float* bgp = Bg + (size_t)(kg * 8) * ldb + nt * BN + wn * (BN / 2) + fr;
  const float* bup = Bu + (size_t)(kg * 8) * ldb + nt * BN + wn * (BN / 2) + fr;

  for (int mt = mt0; mt < mtE; ++mt) {
    const uint16_t* ab[MF];
#pragma unroll
    for (int mf = 0; mf < MF; ++mf) {
      const int slot = mt * BM + wm * (BM / 2) + mf * 16 + fr;
      if constexpr (GATHER) {
        const int idx = slot < n_e ? slot : 0;
        const int bv = bucket[e * CAP + idx];
        ab[mf] = xb + (size_t)(bv >> 3) * K + kg * 8;
      } else {
        ab[mf] = xb + (size_t)slot * K + kg * 8;
      }
    }

    f32x4 accg[MF][NF] = {};
    f32x4 accu[MF][NF] = {};

#pragma unroll 2
    for (int k0 = 0; k0 < K; k0 += 32) {  // one 32-k slab per iter
      bf16x8 af[MF];
#pragma unroll
      for (int mf = 0; mf < MF; ++mf)
        af[mf] = __builtin_bit_cast(bf16x8, *(const uint4*)(ab[mf] + k0));
      bf16x8 bgf[NF], buf2[NF];
#pragma unroll
      for (int nf = 0; nf < NF; ++nf) {
        const float* p = bgp + (size_t)k0 * ldb + nf * 16;
        const float* q = bup + (size_t)k0 * ldb + nf * 16;
        bf16x8 vg, vu;
#pragma unroll
        for (int j = 0; j < 8; ++j) {
          vg[j] = (__bf16)p[(size_t)j * ldb];
          vu[j] = (__bf16)q[(size_t)j * ldb];
        }
        bgf[nf] = vg;
        buf2[nf] = vu;
      }
#pragma unroll
      for (int mf = 0; mf < MF; ++mf)
#pragma unroll
        for (int nf = 0; nf < NF; ++nf) {
          accg[mf][nf] = __builtin_amdgcn_mfma_f32_16x16x32_bf16(
              af[mf], bgf[nf], accg[mf][nf], 0, 0, 0);
          accu[mf][nf] = __builtin_amdgcn_mfma_f32_16x16x32_bf16(
              af[mf], buf2[nf], accu[mf][nf], 0, 0, 0);
        }
    }

    const int col0 = nt * BN + wn * (BN / 2) + fr;
#pragma unroll
    for (int mf = 0; mf < MF; ++mf)
#pragma unroll
      for (int rr = 0; rr < 4; ++rr) {
        const int slot = mt * BM + wm * (BM / 2) + mf * 16 + kg * 4 + rr;
        if (slot < n_e) {
          const size_t ro = (size_t)slot * ldb + col0;
#pragma unroll
          for (int nf = 0; nf < NF; ++nf) {
            const float g = accg[mf][nf][rr], u = accu[mf][nf][rr];
            actE[ro + nf * 16] = f2bf(g / (1.f + expf(-g)) * u);
          }
        }
      }
  }
}

// ---------------- down GEMM, LDS-free; GATHER -> weighted bf16 into ybuf ----
template <int BM, int BN, bool GATHER>
__global__ __launch_bounds__(256) void ffn_down(
    const uint16_t* __restrict__ act, const float* __restrict__ Wd,
    void* __restrict__ outp, const int* __restrict__ cnt,
    const int* __restrict__ bucket, const float* __restrict__ bw, const int K) {
  constexpr int MF = BM / 32;
  constexpr int NF = BN / 32;

  int e = 0, nt, mt0, mtE, n_e;
  const float* Bd;
  const uint16_t* actE;
  if constexpr (GATHER) {
    e = blockIdx.x;
    nt = blockIdx.y;
    n_e = min(cnt[e], CAP);
    mt0 = 0;
    mtE = (n_e + BM - 1) / BM;
    actE = act + (size_t)e * CAP * K;
    Bd = Wd + (size_t)e * K * H_DIM;
  } else {
    nt = blockIdx.x;
    mt0 = blockIdx.y;
    mtE = mt0 + 1;
    n_e = gridDim.y * BM;
    actE = act;
    Bd = Wd;
  }
  if (mt0 * BM >= n_e) return;

  const int tid = threadIdx.x;
  const int lane = tid & 63, wid = tid >> 6;
  const int wm = wid >> 1, wn = wid & 1;
  const int fr = lane & 15, kg = lane >> 4;

  const float* bdp = Bd + (size_t)(kg * 8) * H_DIM + nt * BN + wn * (BN / 2) + fr;

  for (int mt = mt0; mt < mtE; ++mt) {
    const uint16_t* ab[MF];
#pragma unroll
    for (int mf = 0; mf < MF; ++mf) {
      const int slot = mt * BM + wm * (BM / 2) + mf * 16 + fr;
      const int idx = slot < n_e ? slot : 0;
      ab[mf] = actE + (size_t)idx * K + kg * 8;
    }

    f32x4 acc[MF][NF] = {};

#pragma unroll 2
    for (int k0 = 0; k0 < K; k0 += 32) {
      bf16x8 af[MF];
#pragma unroll
      for (int mf = 0; mf < MF; ++mf)
        af[mf] = __builtin_bit_cast(bf16x8, *(const uint4*)(ab[mf] + k0));
      bf16x8 bdf[NF];
#pragma unroll
      for (int nf = 0; nf < NF; ++nf) {
        const float* p = bdp + (size_t)k0 * H_DIM + nf * 16;
        bf16x8 vd;
#pragma unroll
        for (int j = 0; j < 8; ++j) vd[j] = (__bf16)p[(size_t)j * H_DIM];
        bdf[nf] = vd;
      }
#pragma unroll
      for (int mf = 0; mf < MF; ++mf)
#pragma unroll
        for (int nf = 0; nf < NF; ++nf)
          acc[mf][nf] = __builtin_amdgcn_mfma_f32_16x16x32_bf16(
              af[mf], bdf[nf], acc[mf][nf], 0, 0, 0);
    }

    const int col0 = nt * BN + wn * (BN / 2) + fr;
#pragma unroll
    for (int mf = 0; mf < MF; ++mf)
#pragma unroll
      for (int rr = 0; rr < 4; ++rr) {
        const int slot = mt * BM + wm * (BM / 2) + mf * 16 + kg * 4 + rr;
        if constexpr (GATHER) {
          if (slot < n_e) {
            const int bv = bucket[e * CAP + slot];
            const float w = bw[e * CAP + slot];
            uint16_t* yb = (uint16_t*)outp + (size_t)bv * H_DIM + col0;
#pragma unroll
            for (int nf = 0; nf < NF; ++nf)
              yb[nf * 16] = f2bf(w * acc[mf][nf][rr]);
          }
        } else {
          float* op = (float*)outp + (size_t)slot * H_DIM + col0;
#pragma unroll
          for (int nf = 0; nf < NF; ++nf) op[nf * 16] = acc[mf][nf][rr];
        }
      }
  }
}

// ---------------- combine: routed[t] = sum_{j<k} ybuf[t*8+j] ----------------
__global__ __launch_bounds__(256) void gather_kernel(
    const uint16_t* __restrict__ ybuf, const int* __restrict__ topk_ptr,
    float* __restrict__ routed) {
  const int t = blockIdx.x;
  const int tid = threadIdx.x;
  int k = topk_ptr[0];
  if (k > TOPK_MAX) k = TOPK_MAX;
  float acc[8] = {};
  const uint16_t* base = ybuf + (size_t)t * 8 * H_DIM + tid * 8;
  for (int j = 0; j < k; ++j) {
    uint4 v = *(const uint4*)(base + (size_t)j * H_DIM);
    const uint16_t* h = (const uint16_t*)&v;
#pragma unroll
    for (int i = 0; i < 8; ++i) acc[i] += bf2f(h[i]);
  }
  float4 o0 = make_float4(acc[0], acc[1], acc[2], acc[3]);
  float4 o1 = make_float4(acc[4], acc[5], acc[6], acc[7]);
  float* op = routed + (size_t)t * H_DIM + tid * 8;
  *(float4*)op = o0;
  *(float4*)(op + 4) = o1;
}

extern "C" void kernel_launch(void* const* d_in, const int* in_sizes, int n_in,
                              void* d_out, int out_size, void* d_ws, size_t ws_size,
                              hipStream_t stream) {
  const float* x = (const float*)d_in[0];
  const float* gw = (const float*)d_in[1];
  const float* w_gate = (const float*)d_in[2];
  const float* w_up = (const float*)d_in[3];
  const float* w_down = (const float*)d_in[4];
  const float* sw_gate = (const float*)d_in[5];
  const float* sw_up = (const float*)d_in[6];
  const float* sw_down = (const float*)d_in[7];
  const int* topk = (const int*)d_in[8];
  const int T = in_sizes[0] / H_DIM;  // 2048

  float* shared_out = (float*)d_out;
  float* routed = shared_out + (size_t)T * H_DIM;

  char* ws = (char*)d_ws;
  size_t off = 0;
  auto take = [&](size_t b) {
    char* p = ws + off;
    off += (b + 255) & ~(size_t)255;
    return p;
  };
  uint16_t* xb = (uint16_t*)take((size_t)T * H_DIM * 2);              // 8.4 MB
  int* cnt = (int*)take(E_NUM * 4);
  int* bucket = (int*)take((size_t)E_NUM * CAP * 4);
  float* bw = (float*)take((size_t)E_NUM * CAP * 4);
  uint16_t* act = (uint16_t*)take((size_t)E_NUM * CAP * I_DIM * 2);   // 33.5 MB
  uint16_t* s_act = (uint16_t*)take((size_t)T * IS_DIM * 2);          // 4.2 MB
  uint16_t* ybuf = (uint16_t*)take((size_t)T * 8 * H_DIM * 2);        // 67 MB

  hipMemsetAsync(cnt, 0, E_NUM * 4, stream);

  router_kernel<<<T, 256, 0, stream>>>(x, gw, topk, cnt, bucket, bw, xb);

  // grouped gate+up: BM=256 BN=32, grid (e, nt)
  ffn_in<256, 32, true><<<dim3(E_NUM, I_DIM / 32), 256, 0, stream>>>(
      xb, w_gate, w_up, act, cnt, bucket, H_DIM, I_DIM);
  // shared gate+up: BM=128 BN=32
  ffn_in<128, 32, false><<<dim3(IS_DIM / 32, T / 128), 256, 0, stream>>>(
      xb, sw_gate, sw_up, s_act, nullptr, nullptr, H_DIM, IS_DIM);
  // grouped down: BM=256 BN=64 -> weighted bf16 rows in ybuf
  ffn_down<256, 64, true><<<dim3(E_NUM, H_DIM / 64), 256, 0, stream>>>(
      act, w_down, (void*)ybuf, cnt, bucket, bw, I_DIM);
  // shared down: BM=128 BN=32 -> shared_out (f32)
  ffn_down<128, 32, false><<<dim3(H_DIM / 32, T / 128), 256, 0, stream>>>(
      s_act, sw_down, (void*)shared_out, nullptr, nullptr, nullptr, IS_DIM);
  // combine routed
  gather_kernel<<<T, 256, 0, stream>>>(ybuf, topk, routed);
}

// Round 6
// 431.873 us; speedup vs baseline: 1.7611x; 1.7611x over previous
//
#include <hip/hip_runtime.h>
#include <hip/hip_bf16.h>
#include <stdint.h>

// FusedMoEBlock R5: R3-style GEMMs with double-buffered LDS (B only),
// raw s_barrier (no vmcnt drain) -> weight stream stays in flight across
// K-steps. LDP=68 kills bank conflicts. BK=64.
// T=2048,H=2048,E=64,I=512,IS=1024,k<=8.
// d_out = [shared_out (T*H f32) | routed (T*H f32)].

#define H_DIM 2048
#define E_NUM 64
#define I_DIM 512
#define IS_DIM 1024
#define CAP 512
#define TOPK_MAX 8
#define BK 64
#define LDP 68   // u16 row stride = 34 dwords == 2 mod 32 -> 2-way max (free)

typedef float f32x4 __attribute__((ext_vector_type(4)));
typedef __bf16 bf16x8 __attribute__((ext_vector_type(8)));

__device__ __forceinline__ uint16_t f2bf(float f) {
  union { float f; uint32_t u; } v;
  v.f = f;
  uint32_t r = (v.u + 0x7FFFu + ((v.u >> 16) & 1u)) >> 16;  // RNE
  return (uint16_t)r;
}
__device__ __forceinline__ uint32_t pack2(float a, float b) {
  return (uint32_t)f2bf(a) | ((uint32_t)f2bf(b) << 16);
}
__device__ __forceinline__ float bf2f(uint16_t b) {
  union { uint32_t u; float f; } v;
  v.u = (uint32_t)b << 16;
  return v.f;
}

// barrier WITHOUT vmcnt drain: LDS writes complete, global loads stay in flight
#define BAR()                                              \
  do {                                                     \
    asm volatile("s_waitcnt lgkmcnt(0)" ::: "memory");     \
    __builtin_amdgcn_s_barrier();                          \
    asm volatile("" ::: "memory");                         \
  } while (0)

// ---------------- router: logits -> sigmoid -> top-k -> buckets; writes xb --
__global__ __launch_bounds__(256) void router_kernel(
    const float* __restrict__ x, const float* __restrict__ gw,
    const int* __restrict__ topk_ptr, int* __restrict__ cnt,
    int* __restrict__ bucket, float* __restrict__ bw,
    uint16_t* __restrict__ xb) {
  const int t = blockIdx.x;
  const int tid = threadIdx.x;
  __shared__ float xs[H_DIM];
  __shared__ float logits[E_NUM];
#pragma unroll
  for (int i = 0; i < 2; ++i) {
    int idx = tid + i * 256;
    *(float4*)(&xs[idx * 4]) = *(const float4*)(x + (size_t)t * H_DIM + idx * 4);
  }
  __syncthreads();
  {  // fused f32->bf16 conversion of this token's row
    const float* p = &xs[tid * 8];
    uint4 o;
    o.x = pack2(p[0], p[1]);
    o.y = pack2(p[2], p[3]);
    o.z = pack2(p[4], p[5]);
    o.w = pack2(p[6], p[7]);
    ((uint4*)(xb + (size_t)t * H_DIM))[tid] = o;
  }
  const int lane = tid & 63, wid = tid >> 6;
  float xr[32];
#pragma unroll
  for (int it = 0; it < 32; ++it) xr[it] = xs[lane + 64 * it];
  for (int eo = 0; eo < 16; ++eo) {
    int e = wid + eo * 4;
    const float* g = gw + (size_t)e * H_DIM;
    float acc = 0.f;
#pragma unroll
    for (int it = 0; it < 32; ++it) acc += xr[it] * g[lane + 64 * it];
#pragma unroll
    for (int off = 32; off; off >>= 1) acc += __shfl_xor(acc, off);
    if (lane == 0) logits[e] = acc;
  }
  __syncthreads();
  if (wid == 0) {
    int k = topk_ptr[0];
    if (k > TOPK_MAX) k = TOPK_MAX;
    // sigmoid; pre-topk normalize is scale-invariant -> skipped
    float v = 1.f / (1.f + expf(-logits[lane]));
    float s = 0.f, myw = 0.f;
    int mye = 0;
    for (int j = 0; j < k; ++j) {
      float m = v;
      int mi = lane;
#pragma unroll
      for (int off = 32; off; off >>= 1) {
        float ov = __shfl_xor(m, off);
        int oi = __shfl_xor(mi, off);
        if (ov > m || (ov == m && oi < mi)) { m = ov; mi = oi; }
      }
      if (lane == j) { myw = m; mye = mi; }
      if (lane == mi) v = -1e30f;
      s += m;
    }
    if (lane < k) {
      float w = myw / s;
      int pos = atomicAdd(&cnt[mye], 1);
      if (pos < CAP) {
        bucket[mye * CAP + pos] = t * 8 + lane;  // token*8 + choice slot
        bw[mye * CAP + pos] = w;
      }
    }
  }
}

// ---------------- gate+up GEMM + silu*mul -> act (bf16) ----------------
// 4 waves, M-split (each wave BM/4 rows x all BN cols). B double-buffered LDS.
template <int BM, int BN, bool GATHER>
__global__ __launch_bounds__(256) void ffn_in(
    const uint16_t* __restrict__ xb, const float* __restrict__ Wg,
    const float* __restrict__ Wu, uint16_t* __restrict__ act,
    const int* __restrict__ cnt, const int* __restrict__ bucket,
    const int K, const int ldb) {
  constexpr int MF = BM / 64;     // row frags per wave
  constexpr int NF = BN / 16;     // col frags per wave (WN=1)
  constexpr int CG = BN / 4;      // B col groups
  constexpr int PG = 256 / CG;    // k-pairs per pass
  constexpr int PAIRS = 32 / PG;  // passes to cover BK/2 kpairs

  int e = 0, nt, mt0, mtE, n_e;
  const float *Bg, *Bu;
  uint16_t* actE;
  if constexpr (GATHER) {
    e = blockIdx.x;  // gridDim.x=64 -> same-e blocks on XCD e%8
    nt = blockIdx.y;
    n_e = min(cnt[e], CAP);
    mt0 = 0;
    mtE = (n_e + BM - 1) / BM;
    const size_t wo = (size_t)e * K * ldb;
    Bg = Wg + wo;
    Bu = Wu + wo;
    actE = act + (size_t)e * CAP * ldb;
  } else {
    nt = blockIdx.x;
    mt0 = blockIdx.y;
    mtE = mt0 + 1;
    n_e = gridDim.y * BM;
    Bg = Wg;
    Bu = Wu;
    actE = act;
  }

  __shared__ uint16_t Bgs[2][BN][LDP];
  __shared__ uint16_t Bus[2][BN][LDP];

  const int tid = threadIdx.x;
  const int cg4 = (tid % CG) * 4, kp = tid / CG;  // col group, kpair base
  const float* bgp = Bg + (size_t)(2 * kp) * ldb + nt * BN + cg4;
  const float* bup = Bu + (size_t)(2 * kp) * ldb + nt * BN + cg4;

  const int lane = tid & 63, wid = tid >> 6;
  const int fr = lane & 15, kg = lane >> 4;

  float4 g0[PAIRS], g1[PAIRS], u0[PAIRS], u1[PAIRS];

  const int NS = K / BK;
  for (int mt = mt0; mt < mtE; ++mt) {
    const uint16_t* ab[MF];
#pragma unroll
    for (int mf = 0; mf < MF; ++mf) {
      const int slot = mt * BM + wid * (BM / 4) + mf * 16 + fr;
      if constexpr (GATHER) {
        const int idx = slot < n_e ? slot : 0;
        const int bv = bucket[e * CAP + idx];
        ab[mf] = xb + (size_t)(bv >> 3) * K + kg * 8;
      } else {
        ab[mf] = xb + (size_t)slot * K + kg * 8;
      }
    }

    f32x4 accg[MF][NF] = {};
    f32x4 accu[MF][NF] = {};

    // prologue: B(0) -> buf0; issue B(1)
#pragma unroll
    for (int pp = 0; pp < PAIRS; ++pp) {
      const float* g = bgp + (size_t)(2 * pp * PG) * ldb;
      g0[pp] = *(const float4*)g;
      g1[pp] = *(const float4*)(g + ldb);
      const float* u = bup + (size_t)(2 * pp * PG) * ldb;
      u0[pp] = *(const float4*)u;
      u1[pp] = *(const float4*)(u + ldb);
    }
#pragma unroll
    for (int pp = 0; pp < PAIRS; ++pp) {
      const int k2 = 2 * (kp + pp * PG);
      *(uint32_t*)(&Bgs[0][cg4 + 0][k2]) = pack2(g0[pp].x, g1[pp].x);
      *(uint32_t*)(&Bgs[0][cg4 + 1][k2]) = pack2(g0[pp].y, g1[pp].y);
      *(uint32_t*)(&Bgs[0][cg4 + 2][k2]) = pack2(g0[pp].z, g1[pp].z);
      *(uint32_t*)(&Bgs[0][cg4 + 3][k2]) = pack2(g0[pp].w, g1[pp].w);
      *(uint32_t*)(&Bus[0][cg4 + 0][k2]) = pack2(u0[pp].x, u1[pp].x);
      *(uint32_t*)(&Bus[0][cg4 + 1][k2]) = pack2(u0[pp].y, u1[pp].y);
      *(uint32_t*)(&Bus[0][cg4 + 2][k2]) = pack2(u0[pp].z, u1[pp].z);
      *(uint32_t*)(&Bus[0][cg4 + 3][k2]) = pack2(u0[pp].w, u1[pp].w);
    }
    if (NS > 1) {
#pragma unroll
      for (int pp = 0; pp < PAIRS; ++pp) {
        const float* g = bgp + (size_t)(BK + 2 * pp * PG) * ldb;
        g0[pp] = *(const float4*)g;
        g1[pp] = *(const float4*)(g + ldb);
        const float* u = bup + (size_t)(BK + 2 * pp * PG) * ldb;
        u0[pp] = *(const float4*)u;
        u1[pp] = *(const float4*)(u + ldb);
      }
    }
    BAR();

    int b = 0;
    for (int s = 0; s < NS; ++s) {
      const int k0 = s * BK;
      // (1) A frags for this step (issued before B(s+2) so waits are counted)
      uint4 a[MF][2];
#pragma unroll
      for (int mf = 0; mf < MF; ++mf)
#pragma unroll
        for (int sl = 0; sl < 2; ++sl)
          a[mf][sl] = *(const uint4*)(ab[mf] + k0 + sl * 32);
      // (2) stage B(s+1) regs -> buf b^1
      if (s + 1 < NS) {
#pragma unroll
        for (int pp = 0; pp < PAIRS; ++pp) {
          const int k2 = 2 * (kp + pp * PG);
          *(uint32_t*)(&Bgs[b ^ 1][cg4 + 0][k2]) = pack2(g0[pp].x, g1[pp].x);
          *(uint32_t*)(&Bgs[b ^ 1][cg4 + 1][k2]) = pack2(g0[pp].y, g1[pp].y);
          *(uint32_t*)(&Bgs[b ^ 1][cg4 + 2][k2]) = pack2(g0[pp].z, g1[pp].z);
          *(uint32_t*)(&Bgs[b ^ 1][cg4 + 3][k2]) = pack2(g0[pp].w, g1[pp].w);
          *(uint32_t*)(&Bus[b ^ 1][cg4 + 0][k2]) = pack2(u0[pp].x, u1[pp].x);
          *(uint32_t*)(&Bus[b ^ 1][cg4 + 1][k2]) = pack2(u0[pp].y, u1[pp].y);
          *(uint32_t*)(&Bus[b ^ 1][cg4 + 2][k2]) = pack2(u0[pp].z, u1[pp].z);
          *(uint32_t*)(&Bus[b ^ 1][cg4 + 3][k2]) = pack2(u0[pp].w, u1[pp].w);
        }
      }
      // (3) issue B(s+2) into regs (stays in flight across the barrier)
      if (s + 2 < NS) {
        const int kq = k0 + 2 * BK;
#pragma unroll
        for (int pp = 0; pp < PAIRS; ++pp) {
          const float* g = bgp + (size_t)(kq + 2 * pp * PG) * ldb;
          g0[pp] = *(const float4*)g;
          g1[pp] = *(const float4*)(g + ldb);
          const float* u = bup + (size_t)(kq + 2 * pp * PG) * ldb;
          u0[pp] = *(const float4*)u;
          u1[pp] = *(const float4*)(u + ldb);
        }
      }
      // (4) MFMA on buf b
#pragma unroll
      for (int sl = 0; sl < 2; ++sl) {
#pragma unroll
        for (int nf = 0; nf < NF; ++nf) {
          const bf16x8 bg = __builtin_bit_cast(
              bf16x8, *(const uint4*)(&Bgs[b][nf * 16 + fr][kg * 8 + sl * 32]));
          const bf16x8 bu = __builtin_bit_cast(
              bf16x8, *(const uint4*)(&Bus[b][nf * 16 + fr][kg * 8 + sl * 32]));
#pragma unroll
          for (int mf = 0; mf < MF; ++mf) {
            const bf16x8 af = __builtin_bit_cast(bf16x8, a[mf][sl]);
            accg[mf][nf] = __builtin_amdgcn_mfma_f32_16x16x32_bf16(
                af, bg, accg[mf][nf], 0, 0, 0);
            accu[mf][nf] = __builtin_amdgcn_mfma_f32_16x16x32_bf16(
                af, bu, accu[mf][nf], 0, 0, 0);
          }
        }
      }
      // (5) one raw barrier per step
      BAR();
      b ^= 1;
    }

    const int col0 = nt * BN + fr;
#pragma unroll
    for (int mf = 0; mf < MF; ++mf)
#pragma unroll
      for (int rr = 0; rr < 4; ++rr) {
        const int slot = mt * BM + wid * (BM / 4) + mf * 16 + kg * 4 + rr;
        if (slot < n_e) {
          const size_t ro = (size_t)slot * ldb + col0;
#pragma unroll
          for (int nf = 0; nf < NF; ++nf) {
            const float g = accg[mf][nf][rr], u = accu[mf][nf][rr];
            actE[ro + nf * 16] = f2bf(g / (1.f + expf(-g)) * u);
          }
        }
      }
  }
}

// ---------------- down GEMM; GATHER -> weighted bf16 rows into ybuf ---------
template <int BM, int BN, bool GATHER>
__global__ __launch_bounds__(256) void ffn_down(
    const uint16_t* __restrict__ act, const float* __restrict__ Wd,
    void* __restrict__ outp, const int* __restrict__ cnt,
    const int* __restrict__ bucket, const float* __restrict__ bw, const int K) {
  constexpr int MF = BM / 64;
  constexpr int NF = BN / 16;
  constexpr int CG = BN / 4;
  constexpr int PG = 256 / CG;
  constexpr int PAIRS = 32 / PG;

  int e = 0, nt, mt0, mtE, n_e;
  const float* Bd;
  const uint16_t* actE;
  if constexpr (GATHER) {
    e = blockIdx.x;
    nt = blockIdx.y;
    n_e = min(cnt[e], CAP);
    mt0 = 0;
    mtE = (n_e + BM - 1) / BM;
    actE = act + (size_t)e * CAP * K;
    Bd = Wd + (size_t)e * K * H_DIM;
  } else {
    nt = blockIdx.x;
    mt0 = blockIdx.y;
    mtE = mt0 + 1;
    n_e = gridDim.y * BM;
    actE = act;
    Bd = Wd;
  }

  __shared__ uint16_t Bs[2][BN][LDP];

  const int tid = threadIdx.x;
  const int cg4 = (tid % CG) * 4, kp = tid / CG;
  const float* bdp = Bd + (size_t)(2 * kp) * H_DIM + nt * BN + cg4;

  const int lane = tid & 63, wid = tid >> 6;
  const int fr = lane & 15, kg = lane >> 4;

  float4 d0[PAIRS], d1[PAIRS];
  const int NS = K / BK;

  for (int mt = mt0; mt < mtE; ++mt) {
    const uint16_t* ab[MF];
#pragma unroll
    for (int mf = 0; mf < MF; ++mf) {
      const int slot = mt * BM + wid * (BM / 4) + mf * 16 + fr;
      const int idx = slot < n_e ? slot : 0;
      ab[mf] = actE + (size_t)idx * K + kg * 8;
    }

    f32x4 acc[MF][NF] = {};

#pragma unroll
    for (int pp = 0; pp < PAIRS; ++pp) {
      const float* d = bdp + (size_t)(2 * pp * PG) * H_DIM;
      d0[pp] = *(const float4*)d;
      d1[pp] = *(const float4*)(d + H_DIM);
    }
#pragma unroll
    for (int pp = 0; pp < PAIRS; ++pp) {
      const int k2 = 2 * (kp + pp * PG);
      *(uint32_t*)(&Bs[0][cg4 + 0][k2]) = pack2(d0[pp].x, d1[pp].x);
      *(uint32_t*)(&Bs[0][cg4 + 1][k2]) = pack2(d0[pp].y, d1[pp].y);
      *(uint32_t*)(&Bs[0][cg4 + 2][k2]) = pack2(d0[pp].z, d1[pp].z);
      *(uint32_t*)(&Bs[0][cg4 + 3][k2]) = pack2(d0[pp].w, d1[pp].w);
    }
    if (NS > 1) {
#pragma unroll
      for (int pp = 0; pp < PAIRS; ++pp) {
        const float* d = bdp + (size_t)(BK + 2 * pp * PG) * H_DIM;
        d0[pp] = *(const float4*)d;
        d1[pp] = *(const float4*)(d + H_DIM);
      }
    }
    BAR();

    int b = 0;
    for (int s = 0; s < NS; ++s) {
      const int k0 = s * BK;
      uint4 a[MF][2];
#pragma unroll
      for (int mf = 0; mf < MF; ++mf)
#pragma unroll
        for (int sl = 0; sl < 2; ++sl)
          a[mf][sl] = *(const uint4*)(ab[mf] + k0 + sl * 32);
      if (s + 1 < NS) {
#pragma unroll
        for (int pp = 0; pp < PAIRS; ++pp) {
          const int k2 = 2 * (kp + pp * PG);
          *(uint32_t*)(&Bs[b ^ 1][cg4 + 0][k2]) = pack2(d0[pp].x, d1[pp].x);
          *(uint32_t*)(&Bs[b ^ 1][cg4 + 1][k2]) = pack2(d0[pp].y, d1[pp].y);
          *(uint32_t*)(&Bs[b ^ 1][cg4 + 2][k2]) = pack2(d0[pp].z, d1[pp].z);
          *(uint32_t*)(&Bs[b ^ 1][cg4 + 3][k2]) = pack2(d0[pp].w, d1[pp].w);
        }
      }
      if (s + 2 < NS) {
        const int kq = k0 + 2 * BK;
#pragma unroll
        for (int pp = 0; pp < PAIRS; ++pp) {
          const float* d = bdp + (size_t)(kq + 2 * pp * PG) * H_DIM;
          d0[pp] = *(const float4*)d;
          d1[pp] = *(const float4*)(d + H_DIM);
        }
      }
#pragma unroll
      for (int sl = 0; sl < 2; ++sl) {
#pragma unroll
        for (int nf = 0; nf < NF; ++nf) {
          const bf16x8 bf_ = __builtin_bit_cast(
              bf16x8, *(const uint4*)(&Bs[b][nf * 16 + fr][kg * 8 + sl * 32]));
#pragma unroll
          for (int mf = 0; mf < MF; ++mf) {
            const bf16x8 af = __builtin_bit_cast(bf16x8, a[mf][sl]);
            acc[mf][nf] = __builtin_amdgcn_mfma_f32_16x16x32_bf16(
                af, bf_, acc[mf][nf], 0, 0, 0);
          }
        }
      }
      BAR();
      b ^= 1;
    }

    const int col0 = nt * BN + fr;
#pragma unroll
    for (int mf = 0; mf < MF; ++mf)
#pragma unroll
      for (int rr = 0; rr < 4; ++rr) {
        const int slot = mt * BM + wid * (BM / 4) + mf * 16 + kg * 4 + rr;
        if constexpr (GATHER) {
          if (slot < n_e) {
            const int bv = bucket[e * CAP + slot];
            const float w = bw[e * CAP + slot];
            uint16_t* yb = (uint16_t*)outp + (size_t)bv * H_DIM + col0;
#pragma unroll
            for (int nf = 0; nf < NF; ++nf)
              yb[nf * 16] = f2bf(w * acc[mf][nf][rr]);
          }
        } else {
          float* op = (float*)outp + (size_t)slot * H_DIM + col0;
#pragma unroll
          for (int nf = 0; nf < NF; ++nf) op[nf * 16] = acc[mf][nf][rr];
        }
      }
  }
}

// ---------------- combine: routed[t] = sum_{j<k} ybuf[t*8+j] ----------------
__global__ __launch_bounds__(256) void gather_kernel(
    const uint16_t* __restrict__ ybuf, const int* __restrict__ topk_ptr,
    float* __restrict__ routed) {
  const int t = blockIdx.x;
  const int tid = threadIdx.x;
  int k = topk_ptr[0];
  if (k > TOPK_MAX) k = TOPK_MAX;
  float acc[8] = {};
  const uint16_t* base = ybuf + (size_t)t * 8 * H_DIM + tid * 8;
  for (int j = 0; j < k; ++j) {
    uint4 v = *(const uint4*)(base + (size_t)j * H_DIM);
    const uint16_t* h = (const uint16_t*)&v;
#pragma unroll
    for (int i = 0; i < 8; ++i) acc[i] += bf2f(h[i]);
  }
  float4 o0 = make_float4(acc[0], acc[1], acc[2], acc[3]);
  float4 o1 = make_float4(acc[4], acc[5], acc[6], acc[7]);
  float* op = routed + (size_t)t * H_DIM + tid * 8;
  *(float4*)op = o0;
  *(float4*)(op + 4) = o1;
}

extern "C" void kernel_launch(void* const* d_in, const int* in_sizes, int n_in,
                              void* d_out, int out_size, void* d_ws, size_t ws_size,
                              hipStream_t stream) {
  const float* x = (const float*)d_in[0];
  const float* gw = (const float*)d_in[1];
  const float* w_gate = (const float*)d_in[2];
  const float* w_up = (const float*)d_in[3];
  const float* w_down = (const float*)d_in[4];
  const float* sw_gate = (const float*)d_in[5];
  const float* sw_up = (const float*)d_in[6];
  const float* sw_down = (const float*)d_in[7];
  const int* topk = (const int*)d_in[8];
  const int T = in_sizes[0] / H_DIM;  // 2048

  float* shared_out = (float*)d_out;
  float* routed = shared_out + (size_t)T * H_DIM;

  char* ws = (char*)d_ws;
  size_t off = 0;
  auto take = [&](size_t b) {
    char* p = ws + off;
    off += (b + 255) & ~(size_t)255;
    return p;
  };
  uint16_t* xb = (uint16_t*)take((size_t)T * H_DIM * 2);              // 8.4 MB
  int* cnt = (int*)take(E_NUM * 4);
  int* bucket = (int*)take((size_t)E_NUM * CAP * 4);
  float* bw = (float*)take((size_t)E_NUM * CAP * 4);
  uint16_t* act = (uint16_t*)take((size_t)E_NUM * CAP * I_DIM * 2);   // 33.5 MB
  uint16_t* s_act = (uint16_t*)take((size_t)T * IS_DIM * 2);          // 4.2 MB
  uint16_t* ybuf = (uint16_t*)take((size_t)T * 8 * H_DIM * 2);        // 67 MB

  hipMemsetAsync(cnt, 0, E_NUM * 4, stream);

  router_kernel<<<T, 256, 0, stream>>>(x, gw, topk, cnt, bucket, bw, xb);

  // grouped gate+up: BM=256 BN=32, grid (e, nt) -> XCD-pinned per expert
  ffn_in<256, 32, true><<<dim3(E_NUM, I_DIM / 32), 256, 0, stream>>>(
      xb, w_gate, w_up, act, cnt, bucket, H_DIM, I_DIM);
  // grouped down: BM=256 BN=64 -> weighted bf16 rows in ybuf
  ffn_down<256, 64, true><<<dim3(E_NUM, H_DIM / 64), 256, 0, stream>>>(
      act, w_down, (void*)ybuf, cnt, bucket, bw, I_DIM);
  // combine routed
  gather_kernel<<<T, 256, 0, stream>>>(ybuf, topk, routed);
  // shared gate+up: BM=128 BN=32
  ffn_in<128, 32, false><<<dim3(IS_DIM / 32, T / 128), 256, 0, stream>>>(
      xb, sw_gate, sw_up, s_act, nullptr, nullptr, H_DIM, IS_DIM);
  // shared down: BM=128 BN=64 -> shared_out (f32)
  ffn_down<128, 64, false><<<dim3(H_DIM / 64, T / 128), 256, 0, stream>>>(
      s_act, sw_down, (void*)shared_out, nullptr, nullptr, nullptr, IS_DIM);
}